// Round 17
// baseline (606.928 us; speedup 1.0000x reference)
//
#include <hip/hip_runtime.h>
#include <hip/hip_fp16.h>

#define N_NODES 20000
#define N_EDGES 640000
#define FDIM 64
#define NB 20
#define LN_EPS 1e-5f
#define NW 8

typedef __attribute__((ext_vector_type(8))) short bf16x8;
typedef __attribute__((ext_vector_type(4))) float f32x4;

#define SEL_HI 0x07060302u
#define SEL_LO 0x05040100u
#define MFMA16 __builtin_amdgcn_mfma_f32_16x16x32_bf16

__device__ __forceinline__ float silu_f(float x) { return x / (1.0f + __expf(-x)); }

__device__ __forceinline__ float bcast_lane(float v, int lane) {
    return __int_as_float(__builtin_amdgcn_readlane(__float_as_int(v), lane));
}

__device__ __forceinline__ unsigned bf16_rn(float x) {
    unsigned u = __float_as_uint(x);
    return (u + 0x7FFFu + ((u >> 16) & 1u)) >> 16;
}

__device__ __forceinline__ unsigned pack_split(float x) {
    unsigned h = bf16_rn(x);
    unsigned lo = bf16_rn(x - __uint_as_float(h << 16));
    return (h << 16) | lo;
}

// packed fp16 atomic add: emits global_atomic_pk_add_f16
__device__ __forceinline__ void pk_atomic_add(__half2* addr, float a, float b) {
    unsafeAtomicAdd(addr, __floats2half2_rn(a, b));
}

__device__ __forceinline__ void load_afrag(const unsigned* rowPtr, int kh, int q,
                                           bf16x8* ahi, bf16x8* alo) {
    const uint4 ra = *(const uint4*)(rowPtr + kh * 32 + q * 8);
    const uint4 rb = *(const uint4*)(rowPtr + kh * 32 + q * 8 + 4);
    union { unsigned u[4]; bf16x8 v; } H, L;
    H.u[0] = __builtin_amdgcn_perm(ra.y, ra.x, SEL_HI);
    H.u[1] = __builtin_amdgcn_perm(ra.w, ra.z, SEL_HI);
    H.u[2] = __builtin_amdgcn_perm(rb.y, rb.x, SEL_HI);
    H.u[3] = __builtin_amdgcn_perm(rb.w, rb.z, SEL_HI);
    L.u[0] = __builtin_amdgcn_perm(ra.y, ra.x, SEL_LO);
    L.u[1] = __builtin_amdgcn_perm(ra.w, ra.z, SEL_LO);
    L.u[2] = __builtin_amdgcn_perm(rb.y, rb.x, SEL_LO);
    L.u[3] = __builtin_amdgcn_perm(rb.w, rb.z, SEL_LO);
    *ahi = H.v;
    *alo = L.v;
}

__device__ __forceinline__ void mm3(const unsigned* Bhi, const unsigned* Blo,
                                    bf16x8 ahi, bf16x8 alo, f32x4* acc, int kh, int l) {
#pragma unroll
    for (int c = 0; c < 4; ++c) {
        bf16x8 bh = *(const bf16x8*)(Bhi + (kh * 4 + c) * 256 + l * 4);
        bf16x8 bl = *(const bf16x8*)(Blo + (kh * 4 + c) * 256 + l * 4);
        acc[c] = MFMA16(ahi, bh, acc[c], 0, 0, 0);
        acc[c] = MFMA16(ahi, bl, acc[c], 0, 0, 0);
        acc[c] = MFMA16(alo, bh, acc[c], 0, 0, 0);
    }
}

// ---------------- Kernel A: node MLP ----------------
__global__ __launch_bounds__(256) void node_mlp_kernel(
    const float* __restrict__ atom, const float* __restrict__ W1, const float* __restrict__ b1,
    const float* __restrict__ W2, const float* __restrict__ b2, float* __restrict__ mn)
{
    __shared__ float W1s[FDIM][FDIM];
    __shared__ float W2s[FDIM][FDIM];
    const int f = threadIdx.x, ty = threadIdx.y;
    const int tid = ty * 64 + f;
    for (int i = tid; i < FDIM * FDIM; i += 256) {
        ((float*)W1s)[i] = W1[i];
        ((float*)W2s)[i] = W2[i];
    }
    __syncthreads();
    const float bb1 = b1[f], bb2 = b2[f];
    const int nw = gridDim.x * 4;
    for (int n = blockIdx.x * 4 + ty; n < N_NODES; n += nw) {
        const float a = atom[n * FDIM + f];
        float h = bb1;
        for (int g = 0; g < FDIM; ++g) h += bcast_lane(a, g) * W1s[g][f];
        h = silu_f(h);
        float o = bb2;
        for (int g = 0; g < FDIM; ++g) o += bcast_lane(h, g) * W2s[g][f];
        mn[n * FDIM + f] = o;
    }
}

// ---------------- Kernel B: per-edge MFMA pipeline, shfl-free scatter ----------------
// Per-edge metadata {src,dst,d0,d1,d2} staged in the unused pad words (64..68) of each
// staging row at group top; scatter reads them via 3 broadcast ds_reads per r-block
// (replaces ~50 serial ds_bpermute per group). aUpd = full-lane fp32 atomics into
// atomOut; fUpd = full-lane pk fp16 atomics (even lanes c={0,1}, odd lanes c={2,3}).
__global__ __launch_bounds__(64 * NW, 2) void edge_kernel(
    const float* __restrict__ dist,   // [E,20]
    const float* __restrict__ dir,    // [E,3]
    const int* __restrict__ eidx,     // [2,E] int32
    const float* __restrict__ mn,     // [N,F]
    const float* __restrict__ We,     // [20,F]
    const float* __restrict__ Wq1a, const float* __restrict__ Wq1b,
    const float* __restrict__ Wq2a, const float* __restrict__ Wq2b,
    const float* __restrict__ forceN, // [N,3,F]
    float* __restrict__ atomAcc,      // [N,F]  (pre-init atom_node)
    __half2* __restrict__ fUpd)       // [N*96], zero-init
{
    __shared__ __align__(16) unsigned Bfr[16384];
    __shared__ __align__(16) unsigned WeFr[2048];
    __shared__ __align__(16) unsigned Astg[NW][16][76];   // words 64..68 of each row = edge metadata

    const int l = threadIdx.x;
    const int ty = threadIdx.y;
    const int q = l >> 4, row = l & 15;

    for (int t = ty; t < 32; t += NW) {
        const int mm = t >> 3, kh = (t >> 2) & 1, c = t & 3;
        const float* W = (mm == 0) ? Wq1a : (mm == 1) ? Wq2a : (mm == 2) ? Wq1b : Wq2b;
        const int n = c * 16 + row;
        const int kb = kh * 32 + q * 8;
        unsigned* hiP = &Bfr[(((mm * 2 + 0) * 2 + kh) * 4 + c) * 256 + l * 4];
        unsigned* loP = &Bfr[(((mm * 2 + 1) * 2 + kh) * 4 + c) * 256 + l * 4];
#pragma unroll
        for (int i = 0; i < 4; ++i) {
            float w0 = W[(kb + 2 * i) * FDIM + n];
            float w1 = W[(kb + 2 * i + 1) * FDIM + n];
            unsigned h0 = bf16_rn(w0);
            unsigned l0 = bf16_rn(w0 - __uint_as_float(h0 << 16));
            unsigned h1 = bf16_rn(w1);
            unsigned l1 = bf16_rn(w1 - __uint_as_float(h1 << 16));
            hiP[i] = h0 | (h1 << 16);
            loP[i] = l0 | (l1 << 16);
        }
    }
    for (int c = ty; c < 4; c += NW) {
        const int n = c * 16 + row;
        unsigned* hiP = &WeFr[(0 * 4 + c) * 256 + l * 4];
        unsigned* loP = &WeFr[(1 * 4 + c) * 256 + l * 4];
#pragma unroll
        for (int i = 0; i < 4; ++i) {
            const int k0 = q * 8 + 2 * i, k1 = k0 + 1;
            float w0 = (k0 < NB) ? We[k0 * FDIM + n] : 0.0f;
            float w1 = (k1 < NB) ? We[k1 * FDIM + n] : 0.0f;
            unsigned h0 = bf16_rn(w0);
            unsigned l0 = bf16_rn(w0 - __uint_as_float(h0 << 16));
            unsigned h1 = bf16_rn(w1);
            unsigned l1 = bf16_rn(w1 - __uint_as_float(h1 << 16));
            hiP[i] = h0 | (h1 << 16);
            loP[i] = l0 | (l1 << 16);
        }
    }
    __syncthreads();

    const unsigned* B1aH = Bfr + 0 * 2048; const unsigned* B1aL = Bfr + 1 * 2048;
    const unsigned* B2aH = Bfr + 2 * 2048; const unsigned* B2aL = Bfr + 3 * 2048;
    const unsigned* B1bH = Bfr + 4 * 2048; const unsigned* B1bL = Bfr + 5 * 2048;
    const unsigned* B2bH = Bfr + 6 * 2048; const unsigned* B2bL = Bfr + 7 * 2048;
    const unsigned* WeH = WeFr;            const unsigned* WeL = WeFr + 1024;

    unsigned* stg = &Astg[ty][0][0];
    const unsigned* rowPtr = &Astg[ty][row][0];

    const int ngroups = N_EDGES / 16;
    const int stride = gridDim.x * NW;
    for (int grp = blockIdx.x * NW + ty; grp < ngroups; grp += stride) {
        const int e0 = grp * 16;

        // ---- load + stage edge metadata into row pads ----
        int ev = 0;
        if (l < 32) ev = eidx[(l < 16) ? (e0 + l) : (N_EDGES + e0 + (l - 16))];
        float dv = (l < 48) ? dir[e0 * 3 + l] : 0.0f;
        if (l < 32) stg[(l & 15) * 76 + 64 + (l >> 4)] = (unsigned)ev;
        if (l < 48) stg[(l / 3) * 76 + 66 + (l % 3)] = __float_as_uint(dv);

        // ---- me = dist16x20 @ We20x64 via MFMA ----
        const float* dp = dist + (size_t)(e0 + row) * NB + q * 8;
        float4 da = {0.f, 0.f, 0.f, 0.f}, db = {0.f, 0.f, 0.f, 0.f};
        if (q < 2)       { da = *(const float4*)dp; db = *(const float4*)(dp + 4); }
        else if (q == 2) { da = *(const float4*)dp; }
        unsigned s0 = pack_split(da.x), s1 = pack_split(da.y);
        unsigned s2 = pack_split(da.z), s3 = pack_split(da.w);
        unsigned s4 = pack_split(db.x), s5 = pack_split(db.y);
        unsigned s6 = pack_split(db.z), s7 = pack_split(db.w);
        union { unsigned u[4]; bf16x8 v; } AH, AL;
        AH.u[0] = __builtin_amdgcn_perm(s1, s0, SEL_HI);
        AH.u[1] = __builtin_amdgcn_perm(s3, s2, SEL_HI);
        AH.u[2] = __builtin_amdgcn_perm(s5, s4, SEL_HI);
        AH.u[3] = __builtin_amdgcn_perm(s7, s6, SEL_HI);
        AL.u[0] = __builtin_amdgcn_perm(s1, s0, SEL_LO);
        AL.u[1] = __builtin_amdgcn_perm(s3, s2, SEL_LO);
        AL.u[2] = __builtin_amdgcn_perm(s5, s4, SEL_LO);
        AL.u[3] = __builtin_amdgcn_perm(s7, s6, SEL_LO);

        f32x4 me4[4];
#pragma unroll
        for (int c = 0; c < 4; ++c) me4[c] = (f32x4){0.f, 0.f, 0.f, 0.f};
        mm3(WeH, WeL, AH.v, AL.v, me4, 0, l);
#pragma unroll
        for (int c = 0; c < 4; ++c)
#pragma unroll
            for (int r = 0; r < 4; ++r)
                stg[(q * 4 + r) * 76 + (row + 16 * c)] = __float_as_uint(me4[c][r]);

        // ---- msg pass A: mn gathers only ----
        float p[16];
#pragma unroll
        for (int j = 0; j < 16; ++j) {
            const int src = __builtin_amdgcn_readlane(ev, j);
            const int dst = __builtin_amdgcn_readlane(ev, 16 + j);
            p[j] = mn[(size_t)src * FDIM + l] * mn[(size_t)dst * FDIM + l];
        }
        // ---- msg pass B: full-lane fp32 atomics, no loads ----
#pragma unroll
        for (int j = 0; j < 16; ++j) {
            const int src = __builtin_amdgcn_readlane(ev, j);
            const float m = __uint_as_float(stg[j * 76 + l]) * p[j];
            atomicAdd(&atomAcc[(size_t)src * FDIM + l], m);
            stg[j * 76 + l] = pack_split(m);
        }

        // ---- h-phase ----
        f32x4 acc1[4], acc2[4];
#pragma unroll
        for (int c = 0; c < 4; ++c) {
            acc1[c] = (f32x4){0.f, 0.f, 0.f, 0.f};
            acc2[c] = (f32x4){0.f, 0.f, 0.f, 0.f};
        }
#pragma unroll
        for (int kh = 0; kh < 2; ++kh) {
            bf16x8 ahi, alo;
            load_afrag(rowPtr, kh, q, &ahi, &alo);
            mm3(B1aH, B1aL, ahi, alo, acc1, kh, l);
            mm3(B2aH, B2aL, ahi, alo, acc2, kh, l);
        }
#pragma unroll
        for (int c = 0; c < 4; ++c)
#pragma unroll
            for (int r = 0; r < 4; ++r) {
                acc1[c][r] = silu_f(acc1[c][r]);
                acc2[c][r] = silu_f(acc2[c][r]);
            }

        // ---- e1 = h1@Wq1b ----
#pragma unroll
        for (int c = 0; c < 4; ++c)
#pragma unroll
            for (int r = 0; r < 4; ++r)
                stg[(q * 4 + r) * 76 + (row + 16 * c)] = pack_split(acc1[c][r]);
        f32x4 eacc1[4];
#pragma unroll
        for (int c = 0; c < 4; ++c) eacc1[c] = (f32x4){0.f, 0.f, 0.f, 0.f};
#pragma unroll
        for (int kh = 0; kh < 2; ++kh) {
            bf16x8 ahi, alo;
            load_afrag(rowPtr, kh, q, &ahi, &alo);
            mm3(B1bH, B1bL, ahi, alo, eacc1, kh, l);
        }

        // ---- e2 = h2@Wq2b ----
#pragma unroll
        for (int c = 0; c < 4; ++c)
#pragma unroll
            for (int r = 0; r < 4; ++r)
                stg[(q * 4 + r) * 76 + (row + 16 * c)] = pack_split(acc2[c][r]);
        f32x4 eacc2[4];
#pragma unroll
        for (int c = 0; c < 4; ++c) eacc2[c] = (f32x4){0.f, 0.f, 0.f, 0.f};
#pragma unroll
        for (int kh = 0; kh < 2; ++kh) {
            bf16x8 ahi, alo;
            load_afrag(rowPtr, kh, q, &ahi, &alo);
            mm3(B2bH, B2bL, ahi, alo, eacc2, kh, l);
        }

        // ---- scatter: metadata via broadcast LDS reads; batched fd loads; full-lane pk atomics ----
        const int cA = (l & 1) * 2;       // even lanes c={0,1}, odd lanes c={2,3}
        const int pr = row >> 1;          // pair-row
#pragma unroll
        for (int r = 0; r < 4; ++r) {
            const int eo76 = (q * 4 + r) * 76;
            const uint2 sv = *(const uint2*)&stg[eo76 + 64];   // {src, dst}
            const float2 dd = *(const float2*)&stg[eo76 + 66]; // {d0, d1}
            const float d2 = __uint_as_float(stg[eo76 + 68]);
            const int vs = (int)sv.x, vd = (int)sv.y;
            const float d0 = dd.x, d1 = dd.y;
            const float* fd = forceN + (size_t)vd * 3 * FDIM;
            float f0[4], f1[4], f2[4];
#pragma unroll
            for (int c = 0; c < 4; ++c) {
                const int n = row + 16 * c;
                f0[c] = fd[0 * FDIM + n];
                f1[c] = fd[1 * FDIM + n];
                f2[c] = fd[2 * FDIM + n];
            }
            float v0[4], v1[4], v2[4], p0[4], p1[4], p2[4];
#pragma unroll
            for (int c = 0; c < 4; ++c) {
                v0[c] = eacc1[c][r] * d0 + eacc2[c][r] * f0[c];
                v1[c] = eacc1[c][r] * d1 + eacc2[c][r] * f1[c];
                v2[c] = eacc1[c][r] * d2 + eacc2[c][r] * f2[c];
                p0[c] = __shfl_xor(v0[c], 1, 64);
                p1[c] = __shfl_xor(v1[c], 1, 64);
                p2[c] = __shfl_xor(v2[c], 1, 64);
            }
            __half2* base = fUpd + (size_t)vs * 96;
#pragma unroll
            for (int cc = 0; cc < 2; ++cc) {
                const int c = cA + cc;
                const int idx = pr + 8 * c;
                if (l & 1) {   // odd: partner(first)=even feature, self=odd feature
                    pk_atomic_add(base + 0 * 32 + idx, p0[c], v0[c]);
                    pk_atomic_add(base + 1 * 32 + idx, p1[c], v1[c]);
                    pk_atomic_add(base + 2 * 32 + idx, p2[c], v2[c]);
                } else {
                    pk_atomic_add(base + 0 * 32 + idx, v0[c], p0[c]);
                    pk_atomic_add(base + 1 * 32 + idx, v1[c], p1[c]);
                    pk_atomic_add(base + 2 * 32 + idx, v2[c], p2[c]);
                }
            }
        }
    }
}

// ---------------- Kernel C: reconstruct force + inv_update2 + LayerNorm ----------------
__global__ __launch_bounds__(256) void node_final_kernel(
    const float* __restrict__ forceN,    // original force_node [N,3,F]
    const __half2* __restrict__ fUpd,    // [N*96]
    const float* __restrict__ Wu, const float* __restrict__ gamma, const float* __restrict__ beta,
    float* __restrict__ atomAcc,         // [N,F] in d_out: atom_node + inv1
    float* __restrict__ forceOut)        // [N,3,F] in d_out
{
    __shared__ float Wus[FDIM][FDIM];
    const int f = threadIdx.x, ty = threadIdx.y;
    const int tid = ty * 64 + f;
    for (int i = tid; i < FDIM * FDIM; i += 256) ((float*)Wus)[i] = Wu[i];
    __syncthreads();
    const float gg = gamma[f], bb = beta[f];
    const bool hi = (f & 1);
    const int nw = gridDim.x * 4;
    for (int n = blockIdx.x * 4 + ty; n < N_NODES; n += nw) {
        const __half2 u0 = fUpd[(size_t)n * 96 + 0 * 32 + (f >> 1)];
        const __half2 u1 = fUpd[(size_t)n * 96 + 1 * 32 + (f >> 1)];
        const __half2 u2 = fUpd[(size_t)n * 96 + 2 * 32 + (f >> 1)];
        const float f0 = forceN[((size_t)n * 3 + 0) * FDIM + f] + (hi ? __high2float(u0) : __low2float(u0));
        const float f1 = forceN[((size_t)n * 3 + 1) * FDIM + f] + (hi ? __high2float(u1) : __low2float(u1));
        const float f2 = forceN[((size_t)n * 3 + 2) * FDIM + f] + (hi ? __high2float(u2) : __low2float(u2));
        forceOut[((size_t)n * 3 + 0) * FDIM + f] = f0;
        forceOut[((size_t)n * 3 + 1) * FDIM + f] = f1;
        forceOut[((size_t)n * 3 + 2) * FDIM + f] = f2;

        float r0 = 0.0f, r1 = 0.0f, r2 = 0.0f;
#pragma unroll 8
        for (int g = 0; g < FDIM; ++g) {
            const float w = Wus[g][f];
            r0 += bcast_lane(f0, g) * w;
            r1 += bcast_lane(f1, g) * w;
            r2 += bcast_lane(f2, g) * w;
        }
        float a = atomAcc[(size_t)n * FDIM + f] + (f0 * r0 + f1 * r1 + f2 * r2);
        float s = a;
#pragma unroll
        for (int off = 32; off >= 1; off >>= 1) s += __shfl_xor(s, off, 64);
        const float mu = s * (1.0f / 64.0f);
        const float d = a - mu;
        float v = d * d;
#pragma unroll
        for (int off = 32; off >= 1; off >>= 1) v += __shfl_xor(v, off, 64);
        v *= (1.0f / 64.0f);
        atomAcc[(size_t)n * FDIM + f] = d * rsqrtf(v + LN_EPS) * gg + bb;
    }
}

extern "C" void kernel_launch(void* const* d_in, const int* in_sizes, int n_in,
                              void* d_out, int out_size, void* d_ws, size_t ws_size,
                              hipStream_t stream)
{
    const float* atom_node  = (const float*)d_in[0];
    const float* force_node = (const float*)d_in[1];
    const float* dir_edge   = (const float*)d_in[2];
    const float* dist_edge  = (const float*)d_in[3];
    const int*   edge_index = (const int*)d_in[4];
    const float* W1   = (const float*)d_in[5];
    const float* b1   = (const float*)d_in[6];
    const float* W2   = (const float*)d_in[7];
    const float* b2   = (const float*)d_in[8];
    const float* We   = (const float*)d_in[9];
    const float* Wq1a = (const float*)d_in[10];
    const float* Wq1b = (const float*)d_in[11];
    const float* Wq2a = (const float*)d_in[12];
    const float* Wq2b = (const float*)d_in[13];
    const float* Wu   = (const float*)d_in[14];
    const float* gamma = (const float*)d_in[15];
    const float* beta  = (const float*)d_in[16];

    float* atomOut  = (float*)d_out;
    float* forceOut = (float*)d_out + (size_t)N_NODES * FDIM;

    // ws layout: mn [0, 5.12MB) | fUpd [5.12MB, 12.8MB)
    char* ws = (char*)d_ws;
    float*   mn   = (float*)ws;
    __half2* fUpd = (__half2*)(ws + 5120000);

    (void)hipMemcpyAsync(atomOut, atom_node, (size_t)N_NODES * FDIM * sizeof(float),
                         hipMemcpyDeviceToDevice, stream);
    (void)hipMemsetAsync(fUpd, 0, (size_t)N_NODES * 96 * sizeof(__half2), stream);

    dim3 blk4(64, 4);
    dim3 blkE(64, NW);
    node_mlp_kernel<<<512, blk4, 0, stream>>>(atom_node, W1, b1, W2, b2, mn);
    edge_kernel<<<256, blkE, 0, stream>>>(dist_edge, dir_edge, edge_index, mn, We,
                                          Wq1a, Wq1b, Wq2a, Wq2b, force_node,
                                          atomOut, fUpd);
    node_final_kernel<<<512, blk4, 0, stream>>>(force_node, fUpd, Wu, gamma, beta,
                                                atomOut, forceOut);
}

// Round 18
// 556.701 us; speedup vs baseline: 1.0902x; 1.0902x over previous
//
#include <hip/hip_runtime.h>
#include <hip/hip_fp16.h>

#define N_NODES 20000
#define N_EDGES 640000
#define FDIM 64
#define NB 20
#define LN_EPS 1e-5f
#define NW 8

typedef __attribute__((ext_vector_type(8))) short bf16x8;
typedef __attribute__((ext_vector_type(4))) float f32x4;

#define SEL_HI 0x07060302u
#define SEL_LO 0x05040100u
#define MFMA16 __builtin_amdgcn_mfma_f32_16x16x32_bf16

__device__ __forceinline__ float silu_f(float x) { return x / (1.0f + __expf(-x)); }

__device__ __forceinline__ float bcast_lane(float v, int lane) {
    return __int_as_float(__builtin_amdgcn_readlane(__float_as_int(v), lane));
}

__device__ __forceinline__ unsigned bf16_rn(float x) {
    unsigned u = __float_as_uint(x);
    return (u + 0x7FFFu + ((u >> 16) & 1u)) >> 16;
}

__device__ __forceinline__ unsigned pack_split(float x) {
    unsigned h = bf16_rn(x);
    unsigned lo = bf16_rn(x - __uint_as_float(h << 16));
    return (h << 16) | lo;
}

__device__ __forceinline__ void pk_atomic_add(__half2* addr, float a, float b) {
    unsafeAtomicAdd(addr, __floats2half2_rn(a, b));
}

__device__ __forceinline__ void load_afrag(const unsigned* rowPtr, int kh, int q,
                                           bf16x8* ahi, bf16x8* alo) {
    const uint4 ra = *(const uint4*)(rowPtr + kh * 32 + q * 8);
    const uint4 rb = *(const uint4*)(rowPtr + kh * 32 + q * 8 + 4);
    union { unsigned u[4]; bf16x8 v; } H, L;
    H.u[0] = __builtin_amdgcn_perm(ra.y, ra.x, SEL_HI);
    H.u[1] = __builtin_amdgcn_perm(ra.w, ra.z, SEL_HI);
    H.u[2] = __builtin_amdgcn_perm(rb.y, rb.x, SEL_HI);
    H.u[3] = __builtin_amdgcn_perm(rb.w, rb.z, SEL_HI);
    L.u[0] = __builtin_amdgcn_perm(ra.y, ra.x, SEL_LO);
    L.u[1] = __builtin_amdgcn_perm(ra.w, ra.z, SEL_LO);
    L.u[2] = __builtin_amdgcn_perm(rb.y, rb.x, SEL_LO);
    L.u[3] = __builtin_amdgcn_perm(rb.w, rb.z, SEL_LO);
    *ahi = H.v;
    *alo = L.v;
}

__device__ __forceinline__ void mm3(const unsigned* Bhi, const unsigned* Blo,
                                    bf16x8 ahi, bf16x8 alo, f32x4* acc, int kh, int l) {
#pragma unroll
    for (int c = 0; c < 4; ++c) {
        bf16x8 bh = *(const bf16x8*)(Bhi + (kh * 4 + c) * 256 + l * 4);
        bf16x8 bl = *(const bf16x8*)(Blo + (kh * 4 + c) * 256 + l * 4);
        acc[c] = MFMA16(ahi, bh, acc[c], 0, 0, 0);
        acc[c] = MFMA16(ahi, bl, acc[c], 0, 0, 0);
        acc[c] = MFMA16(alo, bh, acc[c], 0, 0, 0);
    }
}

// ---------------- Kernel A: node MLP ----------------
__global__ __launch_bounds__(256) void node_mlp_kernel(
    const float* __restrict__ atom, const float* __restrict__ W1, const float* __restrict__ b1,
    const float* __restrict__ W2, const float* __restrict__ b2, float* __restrict__ mn)
{
    __shared__ float W1s[FDIM][FDIM];
    __shared__ float W2s[FDIM][FDIM];
    const int f = threadIdx.x, ty = threadIdx.y;
    const int tid = ty * 64 + f;
    for (int i = tid; i < FDIM * FDIM; i += 256) {
        ((float*)W1s)[i] = W1[i];
        ((float*)W2s)[i] = W2[i];
    }
    __syncthreads();
    const float bb1 = b1[f], bb2 = b2[f];
    const int nw = gridDim.x * 4;
    for (int n = blockIdx.x * 4 + ty; n < N_NODES; n += nw) {
        const float a = atom[n * FDIM + f];
        float h = bb1;
        for (int g = 0; g < FDIM; ++g) h += bcast_lane(a, g) * W1s[g][f];
        h = silu_f(h);
        float o = bb2;
        for (int g = 0; g < FDIM; ++g) o += bcast_lane(h, g) * W2s[g][f];
        mn[n * FDIM + f] = o;
    }
}

// ---- phase helpers (wave-local; stg is this group's staging slice) ----
__device__ __forceinline__ void me_phase(unsigned* stg, const float4& da, const float4& db,
                                         const unsigned* WeH, const unsigned* WeL,
                                         int l, int q, int row)
{
    unsigned s0 = pack_split(da.x), s1 = pack_split(da.y);
    unsigned s2 = pack_split(da.z), s3 = pack_split(da.w);
    unsigned s4 = pack_split(db.x), s5 = pack_split(db.y);
    unsigned s6 = pack_split(db.z), s7 = pack_split(db.w);
    union { unsigned u[4]; bf16x8 v; } AH, AL;
    AH.u[0] = __builtin_amdgcn_perm(s1, s0, SEL_HI);
    AH.u[1] = __builtin_amdgcn_perm(s3, s2, SEL_HI);
    AH.u[2] = __builtin_amdgcn_perm(s5, s4, SEL_HI);
    AH.u[3] = __builtin_amdgcn_perm(s7, s6, SEL_HI);
    AL.u[0] = __builtin_amdgcn_perm(s1, s0, SEL_LO);
    AL.u[1] = __builtin_amdgcn_perm(s3, s2, SEL_LO);
    AL.u[2] = __builtin_amdgcn_perm(s5, s4, SEL_LO);
    AL.u[3] = __builtin_amdgcn_perm(s7, s6, SEL_LO);
    f32x4 me4[4];
#pragma unroll
    for (int c = 0; c < 4; ++c) me4[c] = (f32x4){0.f, 0.f, 0.f, 0.f};
    mm3(WeH, WeL, AH.v, AL.v, me4, 0, l);
#pragma unroll
    for (int c = 0; c < 4; ++c)
#pragma unroll
        for (int r = 0; r < 4; ++r)
            stg[(q * 4 + r) * 76 + (row + 16 * c)] = __float_as_uint(me4[c][r]);
}

__device__ __forceinline__ void gather_phase(int ev, const float* __restrict__ mn, int l, float* p)
{
#pragma unroll
    for (int j = 0; j < 16; ++j) {
        const int src = __builtin_amdgcn_readlane(ev, j);
        const int dst = __builtin_amdgcn_readlane(ev, 16 + j);
        p[j] = mn[(size_t)src * FDIM + l] * mn[(size_t)dst * FDIM + l];
    }
}

__device__ __forceinline__ void msg_phase(unsigned* stg, int ev, const float* p,
                                          __half2* __restrict__ aUpd, int l, bool evenLane)
{
#pragma unroll
    for (int j = 0; j < 16; ++j) {
        const int src = __builtin_amdgcn_readlane(ev, j);
        const float m = __uint_as_float(stg[j * 76 + l]) * p[j];
        const float mp = __shfl_xor(m, 1, 64);
        if (evenLane)
            pk_atomic_add(&aUpd[(size_t)src * 32 + (l >> 1)], m, mp);
        stg[j * 76 + l] = pack_split(m);
    }
}

__device__ __forceinline__ void he_phase(unsigned* stg, const unsigned* rowPtr,
    const unsigned* B1aH, const unsigned* B1aL, const unsigned* B2aH, const unsigned* B2aL,
    const unsigned* B1bH, const unsigned* B1bL, const unsigned* B2bH, const unsigned* B2bL,
    f32x4* eacc1, f32x4* eacc2, int l, int q, int row)
{
    f32x4 acc1[4], acc2[4];
#pragma unroll
    for (int c = 0; c < 4; ++c) {
        acc1[c] = (f32x4){0.f, 0.f, 0.f, 0.f};
        acc2[c] = (f32x4){0.f, 0.f, 0.f, 0.f};
    }
#pragma unroll
    for (int kh = 0; kh < 2; ++kh) {
        bf16x8 ahi, alo;
        load_afrag(rowPtr, kh, q, &ahi, &alo);
        mm3(B1aH, B1aL, ahi, alo, acc1, kh, l);
        mm3(B2aH, B2aL, ahi, alo, acc2, kh, l);
    }
#pragma unroll
    for (int c = 0; c < 4; ++c)
#pragma unroll
        for (int r = 0; r < 4; ++r) {
            acc1[c][r] = silu_f(acc1[c][r]);
            acc2[c][r] = silu_f(acc2[c][r]);
        }
#pragma unroll
    for (int c = 0; c < 4; ++c)
#pragma unroll
        for (int r = 0; r < 4; ++r)
            stg[(q * 4 + r) * 76 + (row + 16 * c)] = pack_split(acc1[c][r]);
#pragma unroll
    for (int c = 0; c < 4; ++c) eacc1[c] = (f32x4){0.f, 0.f, 0.f, 0.f};
#pragma unroll
    for (int kh = 0; kh < 2; ++kh) {
        bf16x8 ahi, alo;
        load_afrag(rowPtr, kh, q, &ahi, &alo);
        mm3(B1bH, B1bL, ahi, alo, eacc1, kh, l);
    }
#pragma unroll
    for (int c = 0; c < 4; ++c)
#pragma unroll
        for (int r = 0; r < 4; ++r)
            stg[(q * 4 + r) * 76 + (row + 16 * c)] = pack_split(acc2[c][r]);
#pragma unroll
    for (int c = 0; c < 4; ++c) eacc2[c] = (f32x4){0.f, 0.f, 0.f, 0.f};
#pragma unroll
    for (int kh = 0; kh < 2; ++kh) {
        bf16x8 ahi, alo;
        load_afrag(rowPtr, kh, q, &ahi, &alo);
        mm3(B2bH, B2bL, ahi, alo, eacc2, kh, l);
    }
}

__device__ __forceinline__ void scatter_phase(int ev, float dv,
    const f32x4* eacc1, const f32x4* eacc2,
    const float* __restrict__ forceN, __half2* __restrict__ fUpd,
    int l, int q, int row, bool evenLane)
{
#pragma unroll
    for (int r = 0; r < 4; ++r) {
        const int eo = q * 4 + r;
        const int vs = __shfl(ev, eo);
        const int vd = __shfl(ev, 16 + eo);
        const float d0 = __shfl(dv, eo * 3 + 0);
        const float d1 = __shfl(dv, eo * 3 + 1);
        const float d2 = __shfl(dv, eo * 3 + 2);
        const float* fd = forceN + (size_t)vd * 3 * FDIM;
        float f0[4], f1[4], f2[4];
#pragma unroll
        for (int c = 0; c < 4; ++c) {
            const int n = row + 16 * c;
            f0[c] = fd[0 * FDIM + n];
            f1[c] = fd[1 * FDIM + n];
            f2[c] = fd[2 * FDIM + n];
        }
        __half2* base = fUpd + (size_t)vs * 96;
#pragma unroll
        for (int c = 0; c < 4; ++c) {
            const float v0 = eacc1[c][r] * d0 + eacc2[c][r] * f0[c];
            const float v1 = eacc1[c][r] * d1 + eacc2[c][r] * f1[c];
            const float v2 = eacc1[c][r] * d2 + eacc2[c][r] * f2[c];
            const float p0 = __shfl_xor(v0, 1, 64);
            const float p1 = __shfl_xor(v1, 1, 64);
            const float p2 = __shfl_xor(v2, 1, 64);
            if (evenLane) {
                const int idx = (row >> 1) + 8 * c;
                pk_atomic_add(base + 0 * 32 + idx, v0, p0);
                pk_atomic_add(base + 1 * 32 + idx, v1, p1);
                pk_atomic_add(base + 2 * 32 + idx, v2, p2);
            }
        }
    }
}

// ---------------- Kernel B: two interleaved groups per wave ----------------
__global__ __launch_bounds__(64 * NW, 2) void edge_kernel(
    const float* __restrict__ dist, const float* __restrict__ dir,
    const int* __restrict__ eidx, const float* __restrict__ mn,
    const float* __restrict__ We,
    const float* __restrict__ Wq1a, const float* __restrict__ Wq1b,
    const float* __restrict__ Wq2a, const float* __restrict__ Wq2b,
    const float* __restrict__ forceN,
    __half2* __restrict__ aUpd,       // [N*32], zero-init
    __half2* __restrict__ fUpd)       // [N*96], zero-init
{
    __shared__ __align__(16) unsigned Bfr[16384];            // 64 KB
    __shared__ __align__(16) unsigned WeFr[2048];            // 8 KB
    __shared__ __align__(16) unsigned Astg[2 * NW][16][76];  // 77.8 KB (two slices per wave)

    const int l = threadIdx.x;
    const int ty = threadIdx.y;
    const int q = l >> 4, row = l & 15;
    const bool evenLane = ((l & 1) == 0);

    for (int t = ty; t < 32; t += NW) {
        const int mm = t >> 3, kh = (t >> 2) & 1, c = t & 3;
        const float* W = (mm == 0) ? Wq1a : (mm == 1) ? Wq2a : (mm == 2) ? Wq1b : Wq2b;
        const int n = c * 16 + row;
        const int kb = kh * 32 + q * 8;
        unsigned* hiP = &Bfr[(((mm * 2 + 0) * 2 + kh) * 4 + c) * 256 + l * 4];
        unsigned* loP = &Bfr[(((mm * 2 + 1) * 2 + kh) * 4 + c) * 256 + l * 4];
#pragma unroll
        for (int i = 0; i < 4; ++i) {
            float w0 = W[(kb + 2 * i) * FDIM + n];
            float w1 = W[(kb + 2 * i + 1) * FDIM + n];
            unsigned h0 = bf16_rn(w0);
            unsigned l0 = bf16_rn(w0 - __uint_as_float(h0 << 16));
            unsigned h1 = bf16_rn(w1);
            unsigned l1 = bf16_rn(w1 - __uint_as_float(h1 << 16));
            hiP[i] = h0 | (h1 << 16);
            loP[i] = l0 | (l1 << 16);
        }
    }
    for (int c = ty; c < 4; c += NW) {
        const int n = c * 16 + row;
        unsigned* hiP = &WeFr[(0 * 4 + c) * 256 + l * 4];
        unsigned* loP = &WeFr[(1 * 4 + c) * 256 + l * 4];
#pragma unroll
        for (int i = 0; i < 4; ++i) {
            const int k0 = q * 8 + 2 * i, k1 = k0 + 1;
            float w0 = (k0 < NB) ? We[k0 * FDIM + n] : 0.0f;
            float w1 = (k1 < NB) ? We[k1 * FDIM + n] : 0.0f;
            unsigned h0 = bf16_rn(w0);
            unsigned l0 = bf16_rn(w0 - __uint_as_float(h0 << 16));
            unsigned h1 = bf16_rn(w1);
            unsigned l1 = bf16_rn(w1 - __uint_as_float(h1 << 16));
            hiP[i] = h0 | (h1 << 16);
            loP[i] = l0 | (l1 << 16);
        }
    }
    __syncthreads();

    const unsigned* B1aH = Bfr + 0 * 2048; const unsigned* B1aL = Bfr + 1 * 2048;
    const unsigned* B2aH = Bfr + 2 * 2048; const unsigned* B2aL = Bfr + 3 * 2048;
    const unsigned* B1bH = Bfr + 4 * 2048; const unsigned* B1bL = Bfr + 5 * 2048;
    const unsigned* B2bH = Bfr + 6 * 2048; const unsigned* B2bL = Bfr + 7 * 2048;
    const unsigned* WeH = WeFr;            const unsigned* WeL = WeFr + 1024;

    unsigned* stgA = &Astg[ty][0][0];
    unsigned* stgB = &Astg[ty + NW][0][0];
    const unsigned* rowPtrA = &Astg[ty][row][0];
    const unsigned* rowPtrB = &Astg[ty + NW][row][0];

    const int ngroups = N_EDGES / 16;          // 40000 (even)
    const int stride = gridDim.x * NW * 2;
    for (int base = (blockIdx.x * NW + ty) * 2; base < ngroups; base += stride) {
        const int eA = base * 16;
        const int eB = (base + 1) * 16;

        // ---- loads for both groups (issue together) ----
        int evA = 0, evB = 0;
        if (l < 32) {
            evA = eidx[(l < 16) ? (eA + l) : (N_EDGES + eA + (l - 16))];
            evB = eidx[(l < 16) ? (eB + l) : (N_EDGES + eB + (l - 16))];
        }
        float dvA = (l < 48) ? dir[eA * 3 + l] : 0.0f;
        float dvB = (l < 48) ? dir[eB * 3 + l] : 0.0f;
        float4 daA = {0.f, 0.f, 0.f, 0.f}, dbA = {0.f, 0.f, 0.f, 0.f};
        float4 daB = {0.f, 0.f, 0.f, 0.f}, dbB = {0.f, 0.f, 0.f, 0.f};
        {
            const float* dpA = dist + (size_t)(eA + row) * NB + q * 8;
            const float* dpB = dist + (size_t)(eB + row) * NB + q * 8;
            if (q < 2)       { daA = *(const float4*)dpA; dbA = *(const float4*)(dpA + 4);
                               daB = *(const float4*)dpB; dbB = *(const float4*)(dpB + 4); }
            else if (q == 2) { daA = *(const float4*)dpA; daB = *(const float4*)dpB; }
        }

        // ---- interleaved phases: A then B of each stage ----
        me_phase(stgA, daA, dbA, WeH, WeL, l, q, row);
        me_phase(stgB, daB, dbB, WeH, WeL, l, q, row);

        float pA[16], pB[16];
        gather_phase(evA, mn, l, pA);
        gather_phase(evB, mn, l, pB);

        msg_phase(stgA, evA, pA, aUpd, l, evenLane);
        msg_phase(stgB, evB, pB, aUpd, l, evenLane);

        f32x4 eacc1A[4], eacc2A[4], eacc1B[4], eacc2B[4];
        he_phase(stgA, rowPtrA, B1aH, B1aL, B2aH, B2aL, B1bH, B1bL, B2bH, B2bL,
                 eacc1A, eacc2A, l, q, row);
        he_phase(stgB, rowPtrB, B1aH, B1aL, B2aH, B2aL, B1bH, B1bL, B2bH, B2bL,
                 eacc1B, eacc2B, l, q, row);

        scatter_phase(evA, dvA, eacc1A, eacc2A, forceN, fUpd, l, q, row, evenLane);
        scatter_phase(evB, dvB, eacc1B, eacc2B, forceN, fUpd, l, q, row, evenLane);
    }
}

// ---------------- Kernel C: reconstruct outputs + inv_update2 + LayerNorm ----------------
__global__ __launch_bounds__(256) void node_final_kernel(
    const float* __restrict__ atomN, const float* __restrict__ forceN,
    const __half2* __restrict__ aUpd, const __half2* __restrict__ fUpd,
    const float* __restrict__ Wu, const float* __restrict__ gamma, const float* __restrict__ beta,
    float* __restrict__ atomOut, float* __restrict__ forceOut)
{
    __shared__ float Wus[FDIM][FDIM];
    const int f = threadIdx.x, ty = threadIdx.y;
    const int tid = ty * 64 + f;
    for (int i = tid; i < FDIM * FDIM; i += 256) ((float*)Wus)[i] = Wu[i];
    __syncthreads();
    const float gg = gamma[f], bb = beta[f];
    const bool hi = (f & 1);
    const int nw = gridDim.x * 4;
    for (int n = blockIdx.x * 4 + ty; n < N_NODES; n += nw) {
        const __half2 u0 = fUpd[(size_t)n * 96 + 0 * 32 + (f >> 1)];
        const __half2 u1 = fUpd[(size_t)n * 96 + 1 * 32 + (f >> 1)];
        const __half2 u2 = fUpd[(size_t)n * 96 + 2 * 32 + (f >> 1)];
        const float f0 = forceN[((size_t)n * 3 + 0) * FDIM + f] + (hi ? __high2float(u0) : __low2float(u0));
        const float f1 = forceN[((size_t)n * 3 + 1) * FDIM + f] + (hi ? __high2float(u1) : __low2float(u1));
        const float f2 = forceN[((size_t)n * 3 + 2) * FDIM + f] + (hi ? __high2float(u2) : __low2float(u2));
        forceOut[((size_t)n * 3 + 0) * FDIM + f] = f0;
        forceOut[((size_t)n * 3 + 1) * FDIM + f] = f1;
        forceOut[((size_t)n * 3 + 2) * FDIM + f] = f2;

        float r0 = 0.0f, r1 = 0.0f, r2 = 0.0f;
#pragma unroll 8
        for (int g = 0; g < FDIM; ++g) {
            const float w = Wus[g][f];
            r0 += bcast_lane(f0, g) * w;
            r1 += bcast_lane(f1, g) * w;
            r2 += bcast_lane(f2, g) * w;
        }
        const __half2 ua = aUpd[(size_t)n * 32 + (f >> 1)];
        const float inv1 = hi ? __high2float(ua) : __low2float(ua);
        float a = atomN[(size_t)n * FDIM + f] + inv1 + (f0 * r0 + f1 * r1 + f2 * r2);
        float s = a;
#pragma unroll
        for (int off = 32; off >= 1; off >>= 1) s += __shfl_xor(s, off, 64);
        const float mu = s * (1.0f / 64.0f);
        const float d = a - mu;
        float v = d * d;
#pragma unroll
        for (int off = 32; off >= 1; off >>= 1) v += __shfl_xor(v, off, 64);
        v *= (1.0f / 64.0f);
        atomOut[(size_t)n * FDIM + f] = d * rsqrtf(v + LN_EPS) * gg + bb;
    }
}

extern "C" void kernel_launch(void* const* d_in, const int* in_sizes, int n_in,
                              void* d_out, int out_size, void* d_ws, size_t ws_size,
                              hipStream_t stream)
{
    const float* atom_node  = (const float*)d_in[0];
    const float* force_node = (const float*)d_in[1];
    const float* dir_edge   = (const float*)d_in[2];
    const float* dist_edge  = (const float*)d_in[3];
    const int*   edge_index = (const int*)d_in[4];
    const float* W1   = (const float*)d_in[5];
    const float* b1   = (const float*)d_in[6];
    const float* W2   = (const float*)d_in[7];
    const float* b2   = (const float*)d_in[8];
    const float* We   = (const float*)d_in[9];
    const float* Wq1a = (const float*)d_in[10];
    const float* Wq1b = (const float*)d_in[11];
    const float* Wq2a = (const float*)d_in[12];
    const float* Wq2b = (const float*)d_in[13];
    const float* Wu   = (const float*)d_in[14];
    const float* gamma = (const float*)d_in[15];
    const float* beta  = (const float*)d_in[16];

    float* atomOut  = (float*)d_out;
    float* forceOut = (float*)d_out + (size_t)N_NODES * FDIM;

    // ws layout: mn [0, 5.12MB) | aUpd [5.12, 7.68MB) | fUpd [7.68, 15.36MB)
    char* ws = (char*)d_ws;
    float*   mn   = (float*)ws;
    __half2* aUpd = (__half2*)(ws + 5120000);
    __half2* fUpd = (__half2*)(ws + 7680000);

    (void)hipMemsetAsync(aUpd, 0, (size_t)N_NODES * 32 * sizeof(__half2), stream);
    (void)hipMemsetAsync(fUpd, 0, (size_t)N_NODES * 96 * sizeof(__half2), stream);

    dim3 blk4(64, 4);
    dim3 blkE(64, NW);
    node_mlp_kernel<<<512, blk4, 0, stream>>>(atom_node, W1, b1, W2, b2, mn);
    edge_kernel<<<256, blkE, 0, stream>>>(dist_edge, dir_edge, edge_index, mn, We,
                                          Wq1a, Wq1b, Wq2a, Wq2b, force_node,
                                          aUpd, fUpd);
    node_final_kernel<<<512, blk4, 0, stream>>>(atom_node, force_node, aUpd, fUpd,
                                                Wu, gamma, beta, atomOut, forceOut);
}

// Round 19
// 542.465 us; speedup vs baseline: 1.1188x; 1.0262x over previous
//
#include <hip/hip_runtime.h>
#include <hip/hip_fp16.h>

#define N_NODES 20000
#define N_EDGES 640000
#define FDIM 64
#define NB 20
#define LN_EPS 1e-5f
#define NW 8

typedef __attribute__((ext_vector_type(8))) short bf16x8;
typedef __attribute__((ext_vector_type(4))) float f32x4;

#define SEL_HI 0x07060302u
#define SEL_LO 0x05040100u
#define MFMA16 __builtin_amdgcn_mfma_f32_16x16x32_bf16

__device__ __forceinline__ float silu_f(float x) { return x / (1.0f + __expf(-x)); }

__device__ __forceinline__ float bcast_lane(float v, int lane) {
    return __int_as_float(__builtin_amdgcn_readlane(__float_as_int(v), lane));
}

__device__ __forceinline__ unsigned bf16_rn(float x) {
    unsigned u = __float_as_uint(x);
    return (u + 0x7FFFu + ((u >> 16) & 1u)) >> 16;
}

__device__ __forceinline__ unsigned pack_split(float x) {
    unsigned h = bf16_rn(x);
    unsigned lo = bf16_rn(x - __uint_as_float(h << 16));
    return (h << 16) | lo;
}

// packed fp16 atomic add: emits global_atomic_pk_add_f16 on gfx9xx
__device__ __forceinline__ void pk_atomic_add(__half2* addr, float a, float b) {
    unsafeAtomicAdd(addr, __floats2half2_rn(a, b));
}

__device__ __forceinline__ void load_afrag(const unsigned* rowPtr, int kh, int q,
                                           bf16x8* ahi, bf16x8* alo) {
    const uint4 ra = *(const uint4*)(rowPtr + kh * 32 + q * 8);
    const uint4 rb = *(const uint4*)(rowPtr + kh * 32 + q * 8 + 4);
    union { unsigned u[4]; bf16x8 v; } H, L;
    H.u[0] = __builtin_amdgcn_perm(ra.y, ra.x, SEL_HI);
    H.u[1] = __builtin_amdgcn_perm(ra.w, ra.z, SEL_HI);
    H.u[2] = __builtin_amdgcn_perm(rb.y, rb.x, SEL_HI);
    H.u[3] = __builtin_amdgcn_perm(rb.w, rb.z, SEL_HI);
    L.u[0] = __builtin_amdgcn_perm(ra.y, ra.x, SEL_LO);
    L.u[1] = __builtin_amdgcn_perm(ra.w, ra.z, SEL_LO);
    L.u[2] = __builtin_amdgcn_perm(rb.y, rb.x, SEL_LO);
    L.u[3] = __builtin_amdgcn_perm(rb.w, rb.z, SEL_LO);
    *ahi = H.v;
    *alo = L.v;
}

__device__ __forceinline__ void mm3(const unsigned* Bhi, const unsigned* Blo,
                                    bf16x8 ahi, bf16x8 alo, f32x4* acc, int kh, int l) {
#pragma unroll
    for (int c = 0; c < 4; ++c) {
        bf16x8 bh = *(const bf16x8*)(Bhi + (kh * 4 + c) * 256 + l * 4);
        bf16x8 bl = *(const bf16x8*)(Blo + (kh * 4 + c) * 256 + l * 4);
        acc[c] = MFMA16(ahi, bh, acc[c], 0, 0, 0);
        acc[c] = MFMA16(ahi, bl, acc[c], 0, 0, 0);
        acc[c] = MFMA16(alo, bh, acc[c], 0, 0, 0);
    }
}

// ---------------- Kernel A: node MLP ----------------
__global__ __launch_bounds__(256) void node_mlp_kernel(
    const float* __restrict__ atom, const float* __restrict__ W1, const float* __restrict__ b1,
    const float* __restrict__ W2, const float* __restrict__ b2, float* __restrict__ mn)
{
    __shared__ float W1s[FDIM][FDIM];
    __shared__ float W2s[FDIM][FDIM];
    const int f = threadIdx.x, ty = threadIdx.y;
    const int tid = ty * 64 + f;
    for (int i = tid; i < FDIM * FDIM; i += 256) {
        ((float*)W1s)[i] = W1[i];
        ((float*)W2s)[i] = W2[i];
    }
    __syncthreads();
    const float bb1 = b1[f], bb2 = b2[f];
    const int nw = gridDim.x * 4;
    for (int n = blockIdx.x * 4 + ty; n < N_NODES; n += nw) {
        const float a = atom[n * FDIM + f];
        float h = bb1;
        for (int g = 0; g < FDIM; ++g) h += bcast_lane(a, g) * W1s[g][f];
        h = silu_f(h);
        float o = bb2;
        for (int g = 0; g < FDIM; ++g) o += bcast_lane(h, g) * W2s[g][f];
        mn[n * FDIM + f] = o;
    }
}

// ---------------- Kernel B: per-edge MFMA pipeline, packed-fp16 atomics (best config, R16) ----
__global__ __launch_bounds__(64 * NW, 2) void edge_kernel(
    const float* __restrict__ dist,   // [E,20]
    const float* __restrict__ dir,    // [E,3]
    const int* __restrict__ eidx,     // [2,E] int32
    const float* __restrict__ mn,     // [N,F]
    const float* __restrict__ We,     // [20,F]
    const float* __restrict__ Wq1a, const float* __restrict__ Wq1b,
    const float* __restrict__ Wq2a, const float* __restrict__ Wq2b,
    const float* __restrict__ forceN, // [N,3,F]
    __half2* __restrict__ aUpd,       // [N*32], zero-init
    __half2* __restrict__ fUpd)       // [N*96], zero-init
{
    __shared__ __align__(16) unsigned Bfr[16384];
    __shared__ __align__(16) unsigned WeFr[2048];
    __shared__ __align__(16) unsigned Astg[NW][16][76];

    const int l = threadIdx.x;
    const int ty = threadIdx.y;
    const int q = l >> 4, row = l & 15;
    const bool evenLane = ((l & 1) == 0);

    for (int t = ty; t < 32; t += NW) {
        const int mm = t >> 3, kh = (t >> 2) & 1, c = t & 3;
        const float* W = (mm == 0) ? Wq1a : (mm == 1) ? Wq2a : (mm == 2) ? Wq1b : Wq2b;
        const int n = c * 16 + row;
        const int kb = kh * 32 + q * 8;
        unsigned* hiP = &Bfr[(((mm * 2 + 0) * 2 + kh) * 4 + c) * 256 + l * 4];
        unsigned* loP = &Bfr[(((mm * 2 + 1) * 2 + kh) * 4 + c) * 256 + l * 4];
#pragma unroll
        for (int i = 0; i < 4; ++i) {
            float w0 = W[(kb + 2 * i) * FDIM + n];
            float w1 = W[(kb + 2 * i + 1) * FDIM + n];
            unsigned h0 = bf16_rn(w0);
            unsigned l0 = bf16_rn(w0 - __uint_as_float(h0 << 16));
            unsigned h1 = bf16_rn(w1);
            unsigned l1 = bf16_rn(w1 - __uint_as_float(h1 << 16));
            hiP[i] = h0 | (h1 << 16);
            loP[i] = l0 | (l1 << 16);
        }
    }
    for (int c = ty; c < 4; c += NW) {
        const int n = c * 16 + row;
        unsigned* hiP = &WeFr[(0 * 4 + c) * 256 + l * 4];
        unsigned* loP = &WeFr[(1 * 4 + c) * 256 + l * 4];
#pragma unroll
        for (int i = 0; i < 4; ++i) {
            const int k0 = q * 8 + 2 * i, k1 = k0 + 1;
            float w0 = (k0 < NB) ? We[k0 * FDIM + n] : 0.0f;
            float w1 = (k1 < NB) ? We[k1 * FDIM + n] : 0.0f;
            unsigned h0 = bf16_rn(w0);
            unsigned l0 = bf16_rn(w0 - __uint_as_float(h0 << 16));
            unsigned h1 = bf16_rn(w1);
            unsigned l1 = bf16_rn(w1 - __uint_as_float(h1 << 16));
            hiP[i] = h0 | (h1 << 16);
            loP[i] = l0 | (l1 << 16);
        }
    }
    __syncthreads();

    const unsigned* B1aH = Bfr + 0 * 2048; const unsigned* B1aL = Bfr + 1 * 2048;
    const unsigned* B2aH = Bfr + 2 * 2048; const unsigned* B2aL = Bfr + 3 * 2048;
    const unsigned* B1bH = Bfr + 4 * 2048; const unsigned* B1bL = Bfr + 5 * 2048;
    const unsigned* B2bH = Bfr + 6 * 2048; const unsigned* B2bL = Bfr + 7 * 2048;
    const unsigned* WeH = WeFr;            const unsigned* WeL = WeFr + 1024;

    unsigned* stg = &Astg[ty][0][0];
    const unsigned* rowPtr = &Astg[ty][row][0];

    const int ngroups = N_EDGES / 16;
    const int stride = gridDim.x * NW;
    for (int grp = blockIdx.x * NW + ty; grp < ngroups; grp += stride) {
        const int e0 = grp * 16;

        int ev = 0;
        if (l < 32) ev = eidx[(l < 16) ? (e0 + l) : (N_EDGES + e0 + (l - 16))];
        float dv = (l < 48) ? dir[e0 * 3 + l] : 0.0f;

        // ---- me = dist16x20 @ We20x64 via MFMA ----
        const float* dp = dist + (size_t)(e0 + row) * NB + q * 8;
        float4 da = {0.f, 0.f, 0.f, 0.f}, db = {0.f, 0.f, 0.f, 0.f};
        if (q < 2)       { da = *(const float4*)dp; db = *(const float4*)(dp + 4); }
        else if (q == 2) { da = *(const float4*)dp; }
        unsigned s0 = pack_split(da.x), s1 = pack_split(da.y);
        unsigned s2 = pack_split(da.z), s3 = pack_split(da.w);
        unsigned s4 = pack_split(db.x), s5 = pack_split(db.y);
        unsigned s6 = pack_split(db.z), s7 = pack_split(db.w);
        union { unsigned u[4]; bf16x8 v; } AH, AL;
        AH.u[0] = __builtin_amdgcn_perm(s1, s0, SEL_HI);
        AH.u[1] = __builtin_amdgcn_perm(s3, s2, SEL_HI);
        AH.u[2] = __builtin_amdgcn_perm(s5, s4, SEL_HI);
        AH.u[3] = __builtin_amdgcn_perm(s7, s6, SEL_HI);
        AL.u[0] = __builtin_amdgcn_perm(s1, s0, SEL_LO);
        AL.u[1] = __builtin_amdgcn_perm(s3, s2, SEL_LO);
        AL.u[2] = __builtin_amdgcn_perm(s5, s4, SEL_LO);
        AL.u[3] = __builtin_amdgcn_perm(s7, s6, SEL_LO);

        f32x4 me4[4];
#pragma unroll
        for (int c = 0; c < 4; ++c) me4[c] = (f32x4){0.f, 0.f, 0.f, 0.f};
        mm3(WeH, WeL, AH.v, AL.v, me4, 0, l);
#pragma unroll
        for (int c = 0; c < 4; ++c)
#pragma unroll
            for (int r = 0; r < 4; ++r)
                stg[(q * 4 + r) * 76 + (row + 16 * c)] = __float_as_uint(me4[c][r]);

        // ---- msg pass A: mn gathers only ----
        float p[16];
#pragma unroll
        for (int j = 0; j < 16; ++j) {
            const int src = __builtin_amdgcn_readlane(ev, j);
            const int dst = __builtin_amdgcn_readlane(ev, 16 + j);
            p[j] = mn[(size_t)src * FDIM + l] * mn[(size_t)dst * FDIM + l];
        }
        // ---- msg pass B: packed fp16 atomics (even lanes), no loads ----
#pragma unroll
        for (int j = 0; j < 16; ++j) {
            const int src = __builtin_amdgcn_readlane(ev, j);
            const float m = __uint_as_float(stg[j * 76 + l]) * p[j];
            const float mp = __shfl_xor(m, 1, 64);
            if (evenLane)
                pk_atomic_add(&aUpd[(size_t)src * 32 + (l >> 1)], m, mp);
            stg[j * 76 + l] = pack_split(m);
        }

        // ---- h-phase ----
        f32x4 acc1[4], acc2[4];
#pragma unroll
        for (int c = 0; c < 4; ++c) {
            acc1[c] = (f32x4){0.f, 0.f, 0.f, 0.f};
            acc2[c] = (f32x4){0.f, 0.f, 0.f, 0.f};
        }
#pragma unroll
        for (int kh = 0; kh < 2; ++kh) {
            bf16x8 ahi, alo;
            load_afrag(rowPtr, kh, q, &ahi, &alo);
            mm3(B1aH, B1aL, ahi, alo, acc1, kh, l);
            mm3(B2aH, B2aL, ahi, alo, acc2, kh, l);
        }
#pragma unroll
        for (int c = 0; c < 4; ++c)
#pragma unroll
            for (int r = 0; r < 4; ++r) {
                acc1[c][r] = silu_f(acc1[c][r]);
                acc2[c][r] = silu_f(acc2[c][r]);
            }

        // ---- e1 = h1@Wq1b ----
#pragma unroll
        for (int c = 0; c < 4; ++c)
#pragma unroll
            for (int r = 0; r < 4; ++r)
                stg[(q * 4 + r) * 76 + (row + 16 * c)] = pack_split(acc1[c][r]);
        f32x4 eacc1[4];
#pragma unroll
        for (int c = 0; c < 4; ++c) eacc1[c] = (f32x4){0.f, 0.f, 0.f, 0.f};
#pragma unroll
        for (int kh = 0; kh < 2; ++kh) {
            bf16x8 ahi, alo;
            load_afrag(rowPtr, kh, q, &ahi, &alo);
            mm3(B1bH, B1bL, ahi, alo, eacc1, kh, l);
        }

        // ---- e2 = h2@Wq2b ----
#pragma unroll
        for (int c = 0; c < 4; ++c)
#pragma unroll
            for (int r = 0; r < 4; ++r)
                stg[(q * 4 + r) * 76 + (row + 16 * c)] = pack_split(acc2[c][r]);
        f32x4 eacc2[4];
#pragma unroll
        for (int c = 0; c < 4; ++c) eacc2[c] = (f32x4){0.f, 0.f, 0.f, 0.f};
#pragma unroll
        for (int kh = 0; kh < 2; ++kh) {
            bf16x8 ahi, alo;
            load_afrag(rowPtr, kh, q, &ahi, &alo);
            mm3(B2bH, B2bL, ahi, alo, eacc2, kh, l);
        }

        // ---- scatter: per r-block, batch 12 fd loads, then packed fp16 atomics ----
#pragma unroll
        for (int r = 0; r < 4; ++r) {
            const int eo = q * 4 + r;
            const int vs = __shfl(ev, eo);
            const int vd = __shfl(ev, 16 + eo);
            const float d0 = __shfl(dv, eo * 3 + 0);
            const float d1 = __shfl(dv, eo * 3 + 1);
            const float d2 = __shfl(dv, eo * 3 + 2);
            const float* fd = forceN + (size_t)vd * 3 * FDIM;
            float f0[4], f1[4], f2[4];
#pragma unroll
            for (int c = 0; c < 4; ++c) {
                const int n = row + 16 * c;
                f0[c] = fd[0 * FDIM + n];
                f1[c] = fd[1 * FDIM + n];
                f2[c] = fd[2 * FDIM + n];
            }
            __half2* base = fUpd + (size_t)vs * 96;
#pragma unroll
            for (int c = 0; c < 4; ++c) {
                const float v0 = eacc1[c][r] * d0 + eacc2[c][r] * f0[c];
                const float v1 = eacc1[c][r] * d1 + eacc2[c][r] * f1[c];
                const float v2 = eacc1[c][r] * d2 + eacc2[c][r] * f2[c];
                const float p0 = __shfl_xor(v0, 1, 64);
                const float p1 = __shfl_xor(v1, 1, 64);
                const float p2 = __shfl_xor(v2, 1, 64);
                if (evenLane) {
                    const int idx = (row >> 1) + 8 * c;
                    pk_atomic_add(base + 0 * 32 + idx, v0, p0);
                    pk_atomic_add(base + 1 * 32 + idx, v1, p1);
                    pk_atomic_add(base + 2 * 32 + idx, v2, p2);
                }
            }
        }
    }
}

// ---------------- Kernel C: reconstruct outputs + inv_update2 + LayerNorm ----------------
__global__ __launch_bounds__(256) void node_final_kernel(
    const float* __restrict__ atomN,     // original atom_node [N,F]
    const float* __restrict__ forceN,    // original force_node [N,3,F]
    const __half2* __restrict__ aUpd,    // [N*32]
    const __half2* __restrict__ fUpd,    // [N*96]
    const float* __restrict__ Wu, const float* __restrict__ gamma, const float* __restrict__ beta,
    float* __restrict__ atomOut, float* __restrict__ forceOut)
{
    __shared__ float Wus[FDIM][FDIM];
    const int f = threadIdx.x, ty = threadIdx.y;
    const int tid = ty * 64 + f;
    for (int i = tid; i < FDIM * FDIM; i += 256) ((float*)Wus)[i] = Wu[i];
    __syncthreads();
    const float gg = gamma[f], bb = beta[f];
    const bool hi = (f & 1);
    const int nw = gridDim.x * 4;
    for (int n = blockIdx.x * 4 + ty; n < N_NODES; n += nw) {
        const __half2 u0 = fUpd[(size_t)n * 96 + 0 * 32 + (f >> 1)];
        const __half2 u1 = fUpd[(size_t)n * 96 + 1 * 32 + (f >> 1)];
        const __half2 u2 = fUpd[(size_t)n * 96 + 2 * 32 + (f >> 1)];
        const float f0 = forceN[((size_t)n * 3 + 0) * FDIM + f] + (hi ? __high2float(u0) : __low2float(u0));
        const float f1 = forceN[((size_t)n * 3 + 1) * FDIM + f] + (hi ? __high2float(u1) : __low2float(u1));
        const float f2 = forceN[((size_t)n * 3 + 2) * FDIM + f] + (hi ? __high2float(u2) : __low2float(u2));
        forceOut[((size_t)n * 3 + 0) * FDIM + f] = f0;
        forceOut[((size_t)n * 3 + 1) * FDIM + f] = f1;
        forceOut[((size_t)n * 3 + 2) * FDIM + f] = f2;

        float r0 = 0.0f, r1 = 0.0f, r2 = 0.0f;
#pragma unroll 8
        for (int g = 0; g < FDIM; ++g) {
            const float w = Wus[g][f];
            r0 += bcast_lane(f0, g) * w;
            r1 += bcast_lane(f1, g) * w;
            r2 += bcast_lane(f2, g) * w;
        }
        const __half2 ua = aUpd[(size_t)n * 32 + (f >> 1)];
        const float inv1 = hi ? __high2float(ua) : __low2float(ua);
        float a = atomN[(size_t)n * FDIM + f] + inv1 + (f0 * r0 + f1 * r1 + f2 * r2);
        float s = a;
#pragma unroll
        for (int off = 32; off >= 1; off >>= 1) s += __shfl_xor(s, off, 64);
        const float mu = s * (1.0f / 64.0f);
        const float d = a - mu;
        float v = d * d;
#pragma unroll
        for (int off = 32; off >= 1; off >>= 1) v += __shfl_xor(v, off, 64);
        v *= (1.0f / 64.0f);
        atomOut[(size_t)n * FDIM + f] = d * rsqrtf(v + LN_EPS) * gg + bb;
    }
}

extern "C" void kernel_launch(void* const* d_in, const int* in_sizes, int n_in,
                              void* d_out, int out_size, void* d_ws, size_t ws_size,
                              hipStream_t stream)
{
    const float* atom_node  = (const float*)d_in[0];
    const float* force_node = (const float*)d_in[1];
    const float* dir_edge   = (const float*)d_in[2];
    const float* dist_edge  = (const float*)d_in[3];
    const int*   edge_index = (const int*)d_in[4];
    const float* W1   = (const float*)d_in[5];
    const float* b1   = (const float*)d_in[6];
    const float* W2   = (const float*)d_in[7];
    const float* b2   = (const float*)d_in[8];
    const float* We   = (const float*)d_in[9];
    const float* Wq1a = (const float*)d_in[10];
    const float* Wq1b = (const float*)d_in[11];
    const float* Wq2a = (const float*)d_in[12];
    const float* Wq2b = (const float*)d_in[13];
    const float* Wu   = (const float*)d_in[14];
    const float* gamma = (const float*)d_in[15];
    const float* beta  = (const float*)d_in[16];

    float* atomOut  = (float*)d_out;
    float* forceOut = (float*)d_out + (size_t)N_NODES * FDIM;

    // ws layout: mn [0, 5.12MB) | aUpd [5.12, 7.68MB) | fUpd [7.68, 15.36MB)
    char* ws = (char*)d_ws;
    float*   mn   = (float*)ws;
    __half2* aUpd = (__half2*)(ws + 5120000);
    __half2* fUpd = (__half2*)(ws + 7680000);

    (void)hipMemsetAsync(aUpd, 0, (size_t)N_NODES * 32 * sizeof(__half2), stream);
    (void)hipMemsetAsync(fUpd, 0, (size_t)N_NODES * 96 * sizeof(__half2), stream);

    dim3 blk4(64, 4);
    dim3 blkE(64, NW);
    node_mlp_kernel<<<512, blk4, 0, stream>>>(atom_node, W1, b1, W2, b2, mn);
    edge_kernel<<<256, blkE, 0, stream>>>(dist_edge, dir_edge, edge_index, mn, We,
                                          Wq1a, Wq1b, Wq2a, Wq2b, force_node,
                                          aUpd, fUpd);
    node_final_kernel<<<512, blk4, 0, stream>>>(atom_node, force_node, aUpd, fUpd,
                                                Wu, gamma, beta, atomOut, forceOut);
}